// Round 4
// baseline (271.665 us; speedup 1.0000x reference)
//
#include <hip/hip_runtime.h>
#include <hip/hip_bf16.h>

#define B_    4
#define CIN   64
#define COUT  64
#define KN    16
#define NPTS  32768

typedef __attribute__((ext_vector_type(8))) short short8;
typedef __attribute__((ext_vector_type(4))) float f32x4;
typedef __attribute__((ext_vector_type(4))) int   i32x4;

// ---------------------------------------------------------------------------
// K1: features [B][64][N] f32 -> ft [B][N][64] bf16 (neighbor column = 128B)
// ---------------------------------------------------------------------------
__global__ __launch_bounds__(256) void transpose_feat_kernel(
    const float* __restrict__ f, __hip_bfloat16* __restrict__ ft) {
  __shared__ float tile[64][65];
  const int b    = blockIdx.y;
  const int n0   = blockIdx.x * 64;
  const int lane = threadIdx.x & 63;
  const int g    = threadIdx.x >> 6;
  const float* src = f + (size_t)b * CIN * NPTS + n0;
#pragma unroll
  for (int cc = 0; cc < 16; ++cc)
    tile[cc * 4 + g][lane] = src[(size_t)(cc * 4 + g) * NPTS + lane];
  __syncthreads();
  __hip_bfloat16* dst = ft + ((size_t)b * NPTS + n0) * CIN;
  const int nrow = threadIdx.x >> 5;
  const int c2   = (threadIdx.x & 31) * 2;
#pragma unroll
  for (int pass = 0; pass < 8; ++pass) {
    const int n = pass * 8 + nrow;
    __hip_bfloat162 v = __float22bfloat162_rn(
        make_float2(tile[c2][n], tile[c2 + 1][n]));
    *(__hip_bfloat162*)&dst[(size_t)n * CIN + c2] = v;
  }
}

// ---------------------------------------------------------------------------
// K2: positions [B][3][N] -> pt [B][N][4] float4
// ---------------------------------------------------------------------------
__global__ __launch_bounds__(256) void transpose_pos_kernel(
    const float* __restrict__ p, float4* __restrict__ pt) {
  const int b = blockIdx.y;
  const int n = blockIdx.x * 256 + threadIdx.x;
  const float* src = p + (size_t)b * 3 * NPTS;
  float4 v;
  v.x = src[n];
  v.y = src[NPTS + n];
  v.z = src[2 * NPTS + n];
  v.w = 0.f;
  pt[(size_t)b * NPTS + n] = v;
}

// ---------------------------------------------------------------------------
// K3: weights -> Wt [64 o][256 c'] bf16, with c' = c*4 + d  (d=3 -> wb row)
// ---------------------------------------------------------------------------
__global__ __launch_bounds__(256) void prep_w_kernel(
    const float* __restrict__ wt, const float* __restrict__ wb,
    __hip_bfloat16* __restrict__ Wt) {
  const int t  = blockIdx.x * 256 + threadIdx.x;   // o*256 + c'
  const int o  = t >> 8;
  const int cp = t & 255;
  const int c  = cp >> 2;
  const int d  = cp & 3;
  const float v = (d < 3) ? wt[((size_t)d * 64 + c) * 64 + o]
                          : wb[(size_t)c * 64 + o];
  Wt[t] = __float2bfloat16(v);
}

// ---------------------------------------------------------------------------
// K4: rec[b][n][k] = {idx, dp.x, dp.y, dp.z} (16B).  Sequential idx reads,
// random 16B pos gathers into L2-resident 2MB table, dp computed here so the
// hot gather kernel has zero pos work.  One thread per point, k fully
// unrolled -> 16 independent gathers in flight per lane.
// ---------------------------------------------------------------------------
__global__ __launch_bounds__(256) void prep_rec_kernel(
    const float4* __restrict__ pt, const int* __restrict__ nb,
    i32x4* __restrict__ rec, int chunk_off, int chunk_pts)
{
  const int b    = blockIdx.y;
  const int nloc = blockIdx.x * 256 + threadIdx.x;   // within chunk
  const int n    = chunk_off + nloc;
  const float4* ptb = pt + (size_t)b * NPTS;
  const int*    nbb = nb + (size_t)b * KN * NPTS + n;
  const float4  c   = ptb[n];
  i32x4* rrow = rec + ((size_t)b * chunk_pts + nloc) * KN;
#pragma unroll
  for (int k = 0; k < KN; ++k) {
    const int idx  = nbb[(size_t)k * NPTS];
    const float4 q = ptb[idx];
    i32x4 r;
    r.x = idx;
    r.y = __float_as_int(q.x - c.x);
    r.z = __float_as_int(q.y - c.y);
    r.w = __float_as_int(q.z - c.z);
    __builtin_nontemporal_store(r, rrow + k);
  }
}

// ---------------------------------------------------------------------------
// K5: gather + k-contraction -> T [B][chunk_pts][256] bf16.
// Wave = 8 points.  One point's recs = 256B, loaded as ONE per-lane dword
// (lane l holds dword l).  All 8 rec loads issue in the prologue (in-order
// vmem returns).  Per k: v_readlane broadcasts idx/dp to SGPRs; feature load
// is the only dependent load (saddr global_load_ushort, 128B coalesced).
// XCD swizzle: batch b -> XCDs {2b,2b+1}: 4.2MB bf16 table ~fits 2 L2s.
// ---------------------------------------------------------------------------
__global__ __launch_bounds__(256) void gather_kernel(
    const __hip_bfloat16* __restrict__ ft,   // [B][N][64]
    const unsigned* __restrict__ rec,        // [B][chunk_pts][64 dwords]
    __hip_bfloat16* __restrict__ T,          // [B][chunk_pts][256]
    int chunk_pts)
{
  const int lane = threadIdx.x & 63;
  const int wv   = threadIdx.x >> 6;
  const int per_batch = chunk_pts >> 5;      // blocks per batch (32 pts/blk)
  const int half_sz   = per_batch >> 1;
  const int xcd  = blockIdx.x & 7;
  const int b    = xcd >> 1;
  const int nblock = (xcd & 1) * half_sz + (blockIdx.x >> 3);
  const int nloc = nblock * 32 + wv * 8;     // within chunk

  const unsigned short* fpk =
      (const unsigned short*)ft + (size_t)b * NPTS * CIN;
  const unsigned* rb = rec + ((size_t)b * chunk_pts + nloc) * 64 + lane;

  unsigned rv[8];
#pragma unroll
  for (int p = 0; p < 8; ++p) rv[p] = rb[p * 64];

  unsigned short* Tb =
      (unsigned short*)T + ((size_t)b * chunk_pts + nloc) * 256 + lane * 4;

#pragma unroll
  for (int p = 0; p < 8; ++p) {
    float s0 = 0.f, s1 = 0.f, s2 = 0.f, fs = 0.f;
#pragma unroll
    for (int k = 0; k < KN; ++k) {
      const int   idx = __builtin_amdgcn_readlane(rv[p], 4 * k);
      const float dx  = __int_as_float(__builtin_amdgcn_readlane(rv[p], 4 * k + 1));
      const float dy  = __int_as_float(__builtin_amdgcn_readlane(rv[p], 4 * k + 2));
      const float dz  = __int_as_float(__builtin_amdgcn_readlane(rv[p], 4 * k + 3));
      const unsigned short u = fpk[(size_t)idx * CIN + lane];
      const float fv = __uint_as_float((unsigned)u << 16);
      fs += fv;
      s0 += fv * dx;
      s1 += fv * dy;
      s2 += fv * dz;
    }
    __hip_bfloat162 lo = __float22bfloat162_rn(make_float2(s0, s1));
    __hip_bfloat162 hi = __float22bfloat162_rn(make_float2(s2, fs));
    unsigned long long pk =
        ((unsigned long long)(*(unsigned*)&hi) << 32) | (*(unsigned*)&lo);
    __builtin_nontemporal_store(pk, (unsigned long long*)(Tb + (size_t)p * 256));
  }
}

// ---------------------------------------------------------------------------
// K6: out[b][o][n] = sum_c' Wt[o][c'] * T[n][c'] + bias[o]   via MFMA bf16.
// ---------------------------------------------------------------------------
__global__ __launch_bounds__(256) void gemm_kernel(
    const __hip_bfloat16* __restrict__ T,    // [B][chunk_pts][256]
    const __hip_bfloat16* __restrict__ Wt,   // [64][256]
    const float* __restrict__ bias,          // [64]
    float* __restrict__ out,                 // [B][64][N]
    int chunk_off, int chunk_pts)
{
  const int lane = threadIdx.x & 63;
  const int wv   = threadIdx.x >> 6;
  const int b    = blockIdx.y;
  const int n0   = blockIdx.x * 64;          // within chunk
  const int col  = lane & 15;
  const int krow = lane >> 4;                // 0..3

  const unsigned short* wr =
      (const unsigned short*)Wt + ((size_t)(wv * 16 + col)) * 256 + krow * 8;
  short8 a[8];
#pragma unroll
  for (int kk = 0; kk < 8; ++kk) a[kk] = *(const short8*)(wr + kk * 32);

  const unsigned short* tb =
      (const unsigned short*)T + ((size_t)b * chunk_pts + n0) * 256 + krow * 8;

  f32x4 acc[4];
#pragma unroll
  for (int nt = 0; nt < 4; ++nt) acc[nt] = (f32x4){0.f, 0.f, 0.f, 0.f};

#pragma unroll
  for (int nt = 0; nt < 4; ++nt) {
    const unsigned short* tc = tb + (size_t)(nt * 16 + col) * 256;
#pragma unroll
    for (int kk = 0; kk < 8; ++kk) {
      short8 bf = __builtin_nontemporal_load((const short8*)(tc + kk * 32));
      acc[nt] = __builtin_amdgcn_mfma_f32_16x16x32_bf16(a[kk], bf, acc[nt], 0, 0, 0);
    }
  }

  const float4 bv = *(const float4*)(bias + wv * 16 + krow * 4);
  float* ob = out + ((size_t)b * COUT + wv * 16 + krow * 4) * NPTS
                  + chunk_off + n0 + col;
#pragma unroll
  for (int r = 0; r < 4; ++r) {
    const float badd = (r == 0) ? bv.x : (r == 1) ? bv.y : (r == 2) ? bv.z : bv.w;
    float* orow = ob + (size_t)r * NPTS;
#pragma unroll
    for (int nt = 0; nt < 4; ++nt)
      __builtin_nontemporal_store(acc[nt][r] + badd, orow + nt * 16);
  }
}

// ---------------------------------------------------------------------------
extern "C" void kernel_launch(void* const* d_in, const int* in_sizes, int n_in,
                              void* d_out, int out_size, void* d_ws, size_t ws_size,
                              hipStream_t stream) {
  const float* features = (const float*)d_in[0];   // [B][64][N]
  const float* wtheta   = (const float*)d_in[1];   // [3][64][64]
  const float* wbias    = (const float*)d_in[2];   // [64][64]
  const float* bias     = (const float*)d_in[3];   // [64]
  const int*   nb       = (const int*)  d_in[4];   // [B][16][N]
  const float* pos      = (const float*)d_in[5];   // [B][3][N]
  float* out = (float*)d_out;

  char* ws = (char*)d_ws;
  __hip_bfloat16* ft = (__hip_bfloat16*)ws;                          // 16.78 MB
  float4*         pt = (float4*)(ws + 16777216);                     //  2.10 MB
  __hip_bfloat16* Wt = (__hip_bfloat16*)(ws + 16777216 + 2097152);   // 32 KB
  const size_t t_base = 16777216 + 2097152 + 32768;

  // chunking: per chunk needs B*cp*(256B rec + 512B T)
  const size_t t_avail = (ws_size > t_base) ? ws_size - t_base : 0;
  int nchunk = 1;
  while (nchunk < 16 &&
         (size_t)B_ * (NPTS / nchunk) * 768 > t_avail) nchunk <<= 1;
  const int chunk_pts = NPTS / nchunk;

  i32x4* rec = (i32x4*)(ws + t_base);
  __hip_bfloat16* T =
      (__hip_bfloat16*)(ws + t_base + (size_t)B_ * chunk_pts * 256);

  transpose_feat_kernel<<<dim3(NPTS / 64, B_), 256, 0, stream>>>(features, ft);
  transpose_pos_kernel<<<dim3(NPTS / 256, B_), 256, 0, stream>>>(pos, pt);
  prep_w_kernel<<<64, 256, 0, stream>>>(wtheta, wbias, Wt);

  for (int c = 0; c < nchunk; ++c) {
    const int off = c * chunk_pts;
    prep_rec_kernel<<<dim3(chunk_pts / 256, B_), 256, 0, stream>>>(
        pt, nb, rec, off, chunk_pts);
    gather_kernel<<<B_ * (chunk_pts / 32), 256, 0, stream>>>(
        ft, (const unsigned*)rec, T, chunk_pts);
    gemm_kernel<<<dim3(chunk_pts / 64, B_), 256, 0, stream>>>(
        T, Wt, bias, out, off, chunk_pts);
  }
}

// Round 5
// 149.996 us; speedup vs baseline: 1.8111x; 1.8111x over previous
//
#include <hip/hip_runtime.h>
#include <hip/hip_bf16.h>

#define B_    4
#define CIN   64
#define COUT  64
#define KN    16
#define NPTS  32768
#define NPB   32      // points per block

typedef __attribute__((ext_vector_type(8))) short short8;
typedef __attribute__((ext_vector_type(4))) float f32x4;
typedef __attribute__((ext_vector_type(4))) int   i32x4;

// ---------------------------------------------------------------------------
// K1: features [B][64][N] f32 -> ft [B][N][64] bf16 (neighbor column = 128B)
// ---------------------------------------------------------------------------
__global__ __launch_bounds__(256) void transpose_feat_kernel(
    const float* __restrict__ f, __hip_bfloat16* __restrict__ ft) {
  __shared__ float tile[64][65];
  const int b    = blockIdx.y;
  const int n0   = blockIdx.x * 64;
  const int lane = threadIdx.x & 63;
  const int g    = threadIdx.x >> 6;
  const float* src = f + (size_t)b * CIN * NPTS + n0;
#pragma unroll
  for (int cc = 0; cc < 16; ++cc)
    tile[cc * 4 + g][lane] = src[(size_t)(cc * 4 + g) * NPTS + lane];
  __syncthreads();
  __hip_bfloat16* dst = ft + ((size_t)b * NPTS + n0) * CIN;
  const int nrow = threadIdx.x >> 5;
  const int c2   = (threadIdx.x & 31) * 2;
#pragma unroll
  for (int pass = 0; pass < 8; ++pass) {
    const int n = pass * 8 + nrow;
    __hip_bfloat162 v = __float22bfloat162_rn(
        make_float2(tile[c2][n], tile[c2 + 1][n]));
    *(__hip_bfloat162*)&dst[(size_t)n * CIN + c2] = v;
  }
}

// ---------------------------------------------------------------------------
// K2: positions [B][3][N] -> pt [B][N][4] float4
// ---------------------------------------------------------------------------
__global__ __launch_bounds__(256) void transpose_pos_kernel(
    const float* __restrict__ p, float4* __restrict__ pt) {
  const int b = blockIdx.y;
  const int n = blockIdx.x * 256 + threadIdx.x;
  const float* src = p + (size_t)b * 3 * NPTS;
  float4 v;
  v.x = src[n];
  v.y = src[NPTS + n];
  v.z = src[2 * NPTS + n];
  v.w = 0.f;
  pt[(size_t)b * NPTS + n] = v;
}

// ---------------------------------------------------------------------------
// K3: weights -> Wt [64 o][256 c'] bf16, with c' = c*4 + d  (d=3 -> wb row)
// ---------------------------------------------------------------------------
__global__ __launch_bounds__(256) void prep_w_kernel(
    const float* __restrict__ wt, const float* __restrict__ wb,
    __hip_bfloat16* __restrict__ Wt) {
  const int t  = blockIdx.x * 256 + threadIdx.x;   // o*256 + c'
  const int o  = t >> 8;
  const int cp = t & 255;
  const int c  = cp >> 2;
  const int d  = cp & 3;
  const float v = (d < 3) ? wt[((size_t)d * 64 + c) * 64 + o]
                          : wb[(size_t)c * 64 + o];
  Wt[t] = __float2bfloat16(v);
}

// ---------------------------------------------------------------------------
// K4 (fused): per block = 32 points of one batch.
//  A: 256 threads build 512 recs {idx, dp.xyz} -> LDS recL (stride-17 i32x4:
//     conflict-free b128 writes AND conflict-free phase-B dword reads).
//  B: wave wv owns 8 points; rv[p] = rec dwords from LDS; per (p,k) readlane
//     broadcasts idx/dp to scalars; the only dependent load is the coalesced
//     128B saddr feature gather.  Results -> LDS TL[n][c'] (row stride 544B:
//     <=2-way on the b128 MFMA reads = free).
//  C: out[64 x 32] = Wt(64x256) . TL^T + bias via mfma_f32_16x16x32_bf16
//     (fragment layouts identical to R4's verified gemm).
// XCD swizzle: batch b -> XCDs {2b,2b+1} so its 4.2MB bf16 feature table and
// 512KB pos table stay L2-local.
// ---------------------------------------------------------------------------
__global__ __launch_bounds__(256) void flex_fused_kernel(
    const __hip_bfloat16* __restrict__ ft,   // [B][N][64]
    const float4* __restrict__ pt,           // [B][N]
    const int*    __restrict__ nb,           // [B][16][N]
    const __hip_bfloat16* __restrict__ Wt,   // [64][256]
    const float*  __restrict__ bias,         // [64]
    float*        __restrict__ out)          // [B][64][N]
{
  __shared__ i32x4 recL[NPB * 17];           // 8.5 KB
  __shared__ __hip_bfloat16 TL[NPB][272];    // 17.4 KB (544B row stride)

  const int t    = threadIdx.x;
  const int lane = t & 63;
  const int wv   = t >> 6;

  const int xcd = blockIdx.x & 7;
  const int b   = xcd >> 1;
  const int loc = (xcd & 1) * ((NPTS / NPB) >> 1) + (blockIdx.x >> 3);
  const int n0  = loc * NPB;

  const unsigned short* fpk = (const unsigned short*)ft + (size_t)b * NPTS * CIN;
  const float4* ptb = pt + (size_t)b * NPTS;
  const int*    nbb = nb + (size_t)b * KN * NPTS;

  // ---- phase A ----
  {
    const int p  = t & 31;
    const int kk = t >> 5;                   // 0..7
    const int n  = n0 + p;
    const float4 ctr = ptb[n];
#pragma unroll
    for (int kh = 0; kh < 2; ++kh) {
      const int k   = kk + kh * 8;
      const int idx = nbb[(size_t)k * NPTS + n];     // coalesced 128B/wave
      const float4 q = ptb[idx];                     // random 16B, L2-local
      i32x4 r;
      r.x = idx;
      r.y = __float_as_int(q.x - ctr.x);
      r.z = __float_as_int(q.y - ctr.y);
      r.w = __float_as_int(q.z - ctr.z);
      recL[p * 17 + k] = r;
    }
  }
  __syncthreads();

  // ---- phase B ----
  {
    const unsigned* recD = (const unsigned*)recL;
    unsigned rv[8];
#pragma unroll
    for (int p = 0; p < 8; ++p)
      rv[p] = recD[(wv * 8 + p) * 68 + lane];        // 2 lanes/bank: free

#pragma unroll
    for (int p = 0; p < 8; ++p) {
      float s0 = 0.f, s1 = 0.f, s2 = 0.f, fs = 0.f;
#pragma unroll
      for (int k = 0; k < KN; ++k) {
        const int   idx = __builtin_amdgcn_readlane(rv[p], 4 * k);
        const float dx  = __int_as_float(__builtin_amdgcn_readlane(rv[p], 4 * k + 1));
        const float dy  = __int_as_float(__builtin_amdgcn_readlane(rv[p], 4 * k + 2));
        const float dz  = __int_as_float(__builtin_amdgcn_readlane(rv[p], 4 * k + 3));
        const unsigned short u = fpk[(size_t)idx * CIN + lane];  // 128B coalesced
        const float fv = __uint_as_float((unsigned)u << 16);
        fs += fv;
        s0 += fv * dx;
        s1 += fv * dy;
        s2 += fv * dz;
      }
      __hip_bfloat162 lo = __float22bfloat162_rn(make_float2(s0, s1));
      __hip_bfloat162 hi = __float22bfloat162_rn(make_float2(s2, fs));
      uint2 pk;
      pk.x = *(unsigned*)&lo;
      pk.y = *(unsigned*)&hi;
      *(uint2*)&TL[wv * 8 + p][lane * 4] = pk;       // 8B store
    }
  }
  __syncthreads();

  // ---- phase C ----
  {
    const int col  = lane & 15;
    const int krow = lane >> 4;                      // 0..3
    const unsigned short* wr =
        (const unsigned short*)Wt + (size_t)(wv * 16 + col) * 256 + krow * 8;
    short8 a[8];
#pragma unroll
    for (int kk = 0; kk < 8; ++kk) a[kk] = *(const short8*)(wr + kk * 32);

    f32x4 acc[2];
    acc[0] = (f32x4){0.f, 0.f, 0.f, 0.f};
    acc[1] = (f32x4){0.f, 0.f, 0.f, 0.f};
#pragma unroll
    for (int nt = 0; nt < 2; ++nt) {
      const unsigned short* tc =
          (const unsigned short*)&TL[nt * 16 + col][0] + krow * 8;
#pragma unroll
      for (int kk = 0; kk < 8; ++kk) {
        short8 bf = *(const short8*)(tc + kk * 32);
        acc[nt] = __builtin_amdgcn_mfma_f32_16x16x32_bf16(a[kk], bf, acc[nt], 0, 0, 0);
      }
    }

    const float4 bv = *(const float4*)(bias + wv * 16 + krow * 4);
    float* ob = out + ((size_t)b * COUT + wv * 16 + krow * 4) * NPTS + n0 + col;
#pragma unroll
    for (int r = 0; r < 4; ++r) {
      const float badd = (r == 0) ? bv.x : (r == 1) ? bv.y : (r == 2) ? bv.z : bv.w;
      float* orow = ob + (size_t)r * NPTS;
#pragma unroll
      for (int nt = 0; nt < 2; ++nt)
        __builtin_nontemporal_store(acc[nt][r] + badd, orow + nt * 16);
    }
  }
}

// ---------------------------------------------------------------------------
extern "C" void kernel_launch(void* const* d_in, const int* in_sizes, int n_in,
                              void* d_out, int out_size, void* d_ws, size_t ws_size,
                              hipStream_t stream) {
  const float* features = (const float*)d_in[0];   // [B][64][N]
  const float* wtheta   = (const float*)d_in[1];   // [3][64][64]
  const float* wbias    = (const float*)d_in[2];   // [64][64]
  const float* bias     = (const float*)d_in[3];   // [64]
  const int*   nb       = (const int*)  d_in[4];   // [B][16][N]
  const float* pos      = (const float*)d_in[5];   // [B][3][N]
  float* out = (float*)d_out;

  char* ws = (char*)d_ws;
  __hip_bfloat16* ft = (__hip_bfloat16*)ws;                          // 16.78 MB
  float4*         pt = (float4*)(ws + 16777216);                     //  2.10 MB
  __hip_bfloat16* Wt = (__hip_bfloat16*)(ws + 16777216 + 2097152);   // 32 KB

  transpose_feat_kernel<<<dim3(NPTS / 64, B_), 256, 0, stream>>>(features, ft);
  transpose_pos_kernel<<<dim3(NPTS / 256, B_), 256, 0, stream>>>(pos, pt);
  prep_w_kernel<<<64, 256, 0, stream>>>(wtheta, wbias, Wt);

  flex_fused_kernel<<<B_ * (NPTS / NPB), 256, 0, stream>>>(
      ft, pt, nb, Wt, bias, out);
}

// Round 7
// 147.299 us; speedup vs baseline: 1.8443x; 1.0183x over previous
//
#include <hip/hip_runtime.h>
#include <hip/hip_bf16.h>

#define B_    4
#define CIN   64
#define COUT  64
#define KN    16
#define NPTS  32768
#define NPB   32      // points per block (fused kernel)

typedef __attribute__((ext_vector_type(8))) short short8;
typedef __attribute__((ext_vector_type(4))) float f32x4;
typedef __attribute__((ext_vector_type(4))) int   i32x4;

// ---------------------------------------------------------------------------
// K1 (all prep in ONE launch):
//  - every block: transpose one 64-pt feature tile f32[64][N] -> bf16 [N][64]
//  - threads 0..63: pack the same 64 points' positions -> float4 table
//  - blocks (y==0, x<64): pack Wt [64 o][256 c'] bf16, c' = c*4 + d
// ---------------------------------------------------------------------------
__global__ __launch_bounds__(256) void prep_all_kernel(
    const float* __restrict__ f,       // [B][64][N]
    const float* __restrict__ pos,     // [B][3][N]
    const float* __restrict__ wtheta,  // [3][64][64]
    const float* __restrict__ wbias,   // [64][64]
    __hip_bfloat16* __restrict__ ft,   // [B][N][64]
    float4*         __restrict__ pt,   // [B][N]
    __hip_bfloat16* __restrict__ Wt)   // [64][256]
{
  __shared__ float tile[64][65];
  const int b    = blockIdx.y;
  const int n0   = blockIdx.x * 64;
  const int lane = threadIdx.x & 63;
  const int g    = threadIdx.x >> 6;
  const float* src = f + (size_t)b * CIN * NPTS + n0;
#pragma unroll
  for (int cc = 0; cc < 16; ++cc)
    tile[cc * 4 + g][lane] = src[(size_t)(cc * 4 + g) * NPTS + lane];
  __syncthreads();
  __hip_bfloat16* dst = ft + ((size_t)b * NPTS + n0) * CIN;
  const int nrow = threadIdx.x >> 5;
  const int c2   = (threadIdx.x & 31) * 2;
#pragma unroll
  for (int pass = 0; pass < 8; ++pass) {
    const int n = pass * 8 + nrow;
    __hip_bfloat162 v = __float22bfloat162_rn(
        make_float2(tile[c2][n], tile[c2 + 1][n]));
    *(__hip_bfloat162*)&dst[(size_t)n * CIN + c2] = v;
  }

  // pos pack for this tile's 64 points
  if (threadIdx.x < 64) {
    const int n = n0 + threadIdx.x;
    const float* ps = pos + (size_t)b * 3 * NPTS;
    float4 v;
    v.x = ps[n]; v.y = ps[NPTS + n]; v.z = ps[2 * NPTS + n]; v.w = 0.f;
    pt[(size_t)b * NPTS + n] = v;
  }

  // Wt pack (64 blocks x 256 threads = 16384 entries)
  if (b == 0 && blockIdx.x < 64) {
    const int t  = blockIdx.x * 256 + threadIdx.x;   // o*256 + c'
    const int o  = t >> 8;
    const int cp = t & 255;
    const int c  = cp >> 2;
    const int d  = cp & 3;
    const float v = (d < 3) ? wtheta[((size_t)d * 64 + c) * 64 + o]
                            : wbias[(size_t)c * 64 + o];
    Wt[t] = __float2bfloat16(v);
  }
}

// ---------------------------------------------------------------------------
// K2 (fused, byte-identical to the R5 version that passed at 61us):
//  A: 256 threads build 512 recs {idx, dp.xyz} -> LDS recL (stride-17 i32x4)
//  B: wave wv owns 8 points; readlane broadcasts idx/dp; only dependent load
//     is the coalesced 128B saddr feature gather; results -> LDS TL
//  C: out[64 x 32] = Wt(64x256) . TL^T + bias via mfma_f32_16x16x32_bf16
// XCD swizzle: batch b -> XCDs {2b,2b+1}.
// ---------------------------------------------------------------------------
__global__ __launch_bounds__(256) void flex_fused_kernel(
    const __hip_bfloat16* __restrict__ ft,   // [B][N][64]
    const float4* __restrict__ pt,           // [B][N]
    const int*    __restrict__ nb,           // [B][16][N]
    const __hip_bfloat16* __restrict__ Wt,   // [64][256]
    const float*  __restrict__ bias,         // [64]
    float*        __restrict__ out)          // [B][64][N]
{
  __shared__ i32x4 recL[NPB * 17];           // 8.5 KB
  __shared__ __hip_bfloat16 TL[NPB][272];    // 17.4 KB (544B row stride)

  const int t    = threadIdx.x;
  const int lane = t & 63;
  const int wv   = t >> 6;

  const int xcd = blockIdx.x & 7;
  const int b   = xcd >> 1;
  const int loc = (xcd & 1) * ((NPTS / NPB) >> 1) + (blockIdx.x >> 3);
  const int n0  = loc * NPB;

  const unsigned short* fpk = (const unsigned short*)ft + (size_t)b * NPTS * CIN;
  const float4* ptb = pt + (size_t)b * NPTS;
  const int*    nbb = nb + (size_t)b * KN * NPTS;

  // ---- phase A ----
  {
    const int p  = t & 31;
    const int kk = t >> 5;                   // 0..7
    const int n  = n0 + p;
    const float4 ctr = ptb[n];
#pragma unroll
    for (int kh = 0; kh < 2; ++kh) {
      const int k   = kk + kh * 8;
      const int idx = nbb[(size_t)k * NPTS + n];     // coalesced 128B/wave
      const float4 q = ptb[idx];                     // random 16B, L2-local
      i32x4 r;
      r.x = idx;
      r.y = __float_as_int(q.x - ctr.x);
      r.z = __float_as_int(q.y - ctr.y);
      r.w = __float_as_int(q.z - ctr.z);
      recL[p * 17 + k] = r;
    }
  }
  __syncthreads();

  // ---- phase B ----
  {
    const unsigned* recD = (const unsigned*)recL;
    unsigned rv[8];
#pragma unroll
    for (int p = 0; p < 8; ++p)
      rv[p] = recD[(wv * 8 + p) * 68 + lane];        // 2 lanes/bank: free

#pragma unroll
    for (int p = 0; p < 8; ++p) {
      float s0 = 0.f, s1 = 0.f, s2 = 0.f, fs = 0.f;
#pragma unroll
      for (int k = 0; k < KN; ++k) {
        const int   idx = __builtin_amdgcn_readlane(rv[p], 4 * k);
        const float dx  = __int_as_float(__builtin_amdgcn_readlane(rv[p], 4 * k + 1));
        const float dy  = __int_as_float(__builtin_amdgcn_readlane(rv[p], 4 * k + 2));
        const float dz  = __int_as_float(__builtin_amdgcn_readlane(rv[p], 4 * k + 3));
        const unsigned short u = fpk[(size_t)idx * CIN + lane];  // 128B coalesced
        const float fv = __uint_as_float((unsigned)u << 16);
        fs += fv;
        s0 += fv * dx;
        s1 += fv * dy;
        s2 += fv * dz;
      }
      __hip_bfloat162 lo = __float22bfloat162_rn(make_float2(s0, s1));
      __hip_bfloat162 hi = __float22bfloat162_rn(make_float2(s2, fs));
      uint2 pk;
      pk.x = *(unsigned*)&lo;
      pk.y = *(unsigned*)&hi;
      *(uint2*)&TL[wv * 8 + p][lane * 4] = pk;       // 8B store
    }
  }
  __syncthreads();

  // ---- phase C ----
  {
    const int col  = lane & 15;
    const int krow = lane >> 4;                      // 0..3
    const unsigned short* wr =
        (const unsigned short*)Wt + (size_t)(wv * 16 + col) * 256 + krow * 8;
    short8 a[8];
#pragma unroll
    for (int kk = 0; kk < 8; ++kk) a[kk] = *(const short8*)(wr + kk * 32);

    f32x4 acc[2];
    acc[0] = (f32x4){0.f, 0.f, 0.f, 0.f};
    acc[1] = (f32x4){0.f, 0.f, 0.f, 0.f};
#pragma unroll
    for (int nt = 0; nt < 2; ++nt) {
      const unsigned short* tc =
          (const unsigned short*)&TL[nt * 16 + col][0] + krow * 8;
#pragma unroll
      for (int kk = 0; kk < 8; ++kk) {
        short8 bf = *(const short8*)(tc + kk * 32);
        acc[nt] = __builtin_amdgcn_mfma_f32_16x16x32_bf16(a[kk], bf, acc[nt], 0, 0, 0);
      }
    }

    const float4 bv = *(const float4*)(bias + wv * 16 + krow * 4);
    float* ob = out + ((size_t)b * COUT + wv * 16 + krow * 4) * NPTS + n0 + col;
#pragma unroll
    for (int r = 0; r < 4; ++r) {
      const float badd = (r == 0) ? bv.x : (r == 1) ? bv.y : (r == 2) ? bv.z : bv.w;
      float* orow = ob + (size_t)r * NPTS;
#pragma unroll
      for (int nt = 0; nt < 2; ++nt)
        __builtin_nontemporal_store(acc[nt][r] + badd, orow + nt * 16);
    }
  }
}

// ---------------------------------------------------------------------------
extern "C" void kernel_launch(void* const* d_in, const int* in_sizes, int n_in,
                              void* d_out, int out_size, void* d_ws, size_t ws_size,
                              hipStream_t stream) {
  const float* features = (const float*)d_in[0];   // [B][64][N]
  const float* wtheta   = (const float*)d_in[1];   // [3][64][64]
  const float* wbias    = (const float*)d_in[2];   // [64][64]
  const float* bias     = (const float*)d_in[3];   // [64]
  const int*   nb       = (const int*)  d_in[4];   // [B][16][N]
  const float* pos      = (const float*)d_in[5];   // [B][3][N]
  float* out = (float*)d_out;

  char* ws = (char*)d_ws;
  __hip_bfloat16* ft = (__hip_bfloat16*)ws;                          // 16.78 MB
  float4*         pt = (float4*)(ws + 16777216);                     //  2.10 MB
  __hip_bfloat16* Wt = (__hip_bfloat16*)(ws + 16777216 + 2097152);   // 32 KB

  prep_all_kernel<<<dim3(NPTS / 64, B_), 256, 0, stream>>>(
      features, pos, wtheta, wbias, ft, pt, Wt);
  flex_fused_kernel<<<B_ * (NPTS / NPB), 256, 0, stream>>>(
      ft, pt, nb, Wt, bias, out);
}